// Round 10
// baseline (7674.402 us; speedup 1.0000x reference)
//
#include <hip/hip_runtime.h>
#include <cstdint>
#include <cstddef>

// ---------------------------------------------------------------------------
// AttentionWordRNN on MI355X — ROUND 7: data-arrival-polling h exchange.
// Round-6 post-mortem: sc0-only loads don't bypass L1 -> stale spin -> hang.
// This round uses ONLY the round-5-proven primitives (__hip_atomic_* RELAXED
// AGENT). Protocol: h replicated per-consumer into sentinel-initialized hx;
// consumers poll data-arrival directly (bf16 pair can never be 0xFFFFFFFF),
// re-poison their exclusive replica after reading; one vmcnt(0) orders
// re-poison before publish. No flags, no fences, no barrier counter.
// ---------------------------------------------------------------------------

#define T_    512
#define B_    64
#define E_    256
#define CD_   128
#define EC_   384      // E + CDIM
#define H_    512
#define NCLS  5
#define NTOK  32768    // T*B

// byte offsets into d_ws
#define OFF_X      0UL
#define OFF_HSC    25165824UL
#define OFF_LOG    92274688UL
#define OFF_ATTN   92405760UL
#define OFF_CTX    92536832UL
#define OFF_WWT    92798976UL
#define OFF_HX     94896128UL
#define WS_REQ     111673344UL

#define SENT_      0xFFFFFFFFu

typedef __attribute__((ext_vector_type(8))) short bf16x8;
typedef __attribute__((ext_vector_type(4))) float f32x4;

__device__ __forceinline__ unsigned short f2bf(float f) {
  union { float f; unsigned u; } v; v.f = f;
  unsigned r = v.u + 0x7FFFu + ((v.u >> 16) & 1u);   // RNE
  return (unsigned short)(r >> 16);
}
__device__ __forceinline__ float bf2f(unsigned short h) {
  union { unsigned u; float f; } v; v.u = ((unsigned)h) << 16;
  return v.f;
}

// ---------------- ws-too-small sentinel ----------------
__global__ void k_sentinel(float* __restrict__ out, int n, float val) {
  int i = blockIdx.x * 64 + threadIdx.x;
  if (i < n) out[i] = val;
}

// ---------------- gather + concat -> x bf16 [NTOK][384] ----------------
__global__ __launch_bounds__(256) void k_gather(
    const int* __restrict__ embed, const float* __restrict__ c_embed,
    const float* __restrict__ etab, unsigned short* __restrict__ x) {
  int idx = blockIdx.x * 256 + threadIdx.x;     // NTOK*48 exact
  int n = idx / 48;
  int q8 = idx - n * 48;
  float f[8];
  if (q8 < 32) {
    int tok = embed[n];
    const float* src = etab + (size_t)tok * E_ + q8 * 8;
#pragma unroll
    for (int j = 0; j < 8; ++j) f[j] = src[j];
  } else {
    const float* src = c_embed + (size_t)n * CD_ + (q8 - 32) * 8;
#pragma unroll
    for (int j = 0; j < 8; ++j) f[j] = src[j];
  }
  union { uint4 v; unsigned short s[8]; } u;
#pragma unroll
  for (int j = 0; j < 8; ++j) u.s[j] = f2bf(f[j]);
  *(uint4*)(x + (size_t)n * EC_ + q8 * 8) = u.v;
}

// ---------------- W_word fp32 [k][d] -> bf16 transposed wwT [d][k] ---------
__global__ __launch_bounds__(256) void k_cvtw(
    const float* __restrict__ Ww, unsigned short* __restrict__ wwT) {
  __shared__ float t[64][65];
  const int kb = blockIdx.x >> 4, db = blockIdx.x & 15;
  const int r = threadIdx.x >> 4, c4 = (threadIdx.x & 15) * 4;
#pragma unroll
  for (int p = 0; p < 4; ++p) {
    float4 v = *(const float4*)(Ww + (size_t)(kb * 64 + p * 16 + r) * 1024
                                + db * 64 + c4);
    t[p * 16 + r][c4 + 0] = v.x; t[p * 16 + r][c4 + 1] = v.y;
    t[p * 16 + r][c4 + 2] = v.z; t[p * 16 + r][c4 + 3] = v.w;
  }
  __syncthreads();
#pragma unroll
  for (int p = 0; p < 4; ++p) {
    union { ushort4 v; unsigned short s[4]; } o;
#pragma unroll
    for (int j = 0; j < 4; ++j) o.s[j] = f2bf(t[c4 + j][p * 16 + r]);
    *(ushort4*)(wwT + (size_t)(db * 64 + p * 16 + r) * 1024 + kb * 64 + c4) = o.v;
  }
}

// ---------------- fused biLSTM scan: x_proj + recurrence, MFMA ----------------
// 128 wgs of 512 thr = dir(2) x bg(4) x ug(16, 32 units); grp = gid&7.
// hx layout: [grp(8)][cons(16)][par(2)][b(16)][jp(256)] dwords (16 MB).
// Consumer polls its exclusive replica for data arrival (!= SENT), re-poisons.
__global__ __launch_bounds__(512) void k_scan(
    const unsigned short* __restrict__ x,
    const float* __restrict__ wih_f, const float* __restrict__ whh_f,
    const float* __restrict__ wih_b, const float* __restrict__ whh_b,
    const float* __restrict__ bias_f, const float* __restrict__ bias_b,
    const float* __restrict__ h0, const float* __restrict__ c0,
    unsigned short* __restrict__ Hsc,            // [T][B][1024] bf16
    unsigned* __restrict__ hx) {
  __shared__ uint4 Bs[1792];                     // 28 ktiles x 64 lanes x 16B
  unsigned long long* const Bs8 = (unsigned long long*)Bs;
  const int tid  = threadIdx.x;
  const int lane = tid & 63;
  const int w    = tid >> 6;                     // wave 0..7
  const int gid  = blockIdx.x;
  const int grp  = gid & 7;                      // dir*4+bg
  const int ug   = gid >> 3;                     // 0..15
  const int dir  = grp >> 2;
  const int bg   = grp & 3;

  const float* wih  = dir ? wih_b  : wih_f;      // [2048][384]
  const float* whh  = dir ? whh_b  : whh_f;      // [2048][512]
  const float* bias = dir ? bias_b : bias_f;     // [2048]

  // ---- preload A fragments (bf16) into registers ----
  bf16x8 afrag[28];
  {
    const int m = lane & 15, koct = lane >> 4;   // A-role: row, k-octet
    const int grow = (m & 3) * H_ + ug * 32 + w * 4 + (m >> 2);
#pragma unroll
    for (int kt = 0; kt < 12; ++kt) {
      const float* src = wih + (size_t)grow * EC_ + kt * 32 + koct * 8;
      union { bf16x8 v; unsigned short s[8]; } u;
#pragma unroll
      for (int j = 0; j < 8; ++j) u.s[j] = f2bf(src[j]);
      afrag[kt] = u.v;
    }
#pragma unroll
    for (int kt = 0; kt < 16; ++kt) {
      const float* src = whh + (size_t)grow * H_ + kt * 32 + koct * 8;
      union { bf16x8 v; unsigned short s[8]; } u;
#pragma unroll
      for (int j = 0; j < 8; ++j) u.s[j] = f2bf(src[j]);
      afrag[12 + kt] = u.v;
    }
  }

  // ---- D-role lane identity: (unit, batch); c-state in register ----
  const int bD = bg * 16 + (lane & 15);
  const int jD = ug * 32 + w * 4 + (lane >> 4);
  float bsv[4];
#pragma unroll
  for (int q = 0; q < 4; ++q) bsv[q] = bias[q * H_ + jD];
  float c = c0[(size_t)dir * B_ * H_ + (size_t)bD * H_ + jD];

  const int sb = tid & 15;                       // staging: batch row
  const int sk = tid >> 4;                       // staging: 0..31

  // producer-side base (lanes bit4==0): [grp][cg][par][lane&15][jpw]
  const int jpw = ug * 16 + w * 2 + (lane >> 5);
  unsigned* const hxp = hx + (size_t)grp * 131072
                        + (size_t)(lane & 15) * 256 + jpw;
  // consumer-side exclusive replica: [grp][ug][par][sb][jp]
  unsigned* const hxc = hx + (size_t)grp * 131072 + (size_t)ug * 8192
                        + (size_t)sb * 256;

  // prefetch x-slice for step 0
  unsigned long long xv[3];
  {
    const int cur0 = dir ? (T_ - 1) : 0;
    const unsigned short* xsrc = x + (size_t)(cur0 * B_ + bg * 16 + sb) * EC_;
#pragma unroll
    for (int p = 0; p < 3; ++p)
      xv[p] = *(const unsigned long long*)(xsrc + (p * 32 + sk) * 4);
  }

  for (int s = 0; s < T_; ++s) {
    const int cur = dir ? (T_ - 1 - s) : s;
    __syncthreads();                             // all waves done with prev Bs
    // stage x part (ktiles 0..11): q = p*32+sk
#pragma unroll
    for (int p = 0; p < 3; ++p) {
      int q = p * 32 + sk;
      Bs8[(q >> 3) * 128 + ((q >> 1) & 3) * 32 + sb * 2 + (q & 1)] = xv[p];
    }

    // issue h reads optimistically (completion checked after x-MFMAs)
    unsigned long long hv[4];
    unsigned long long* hbq = nullptr;
    if (s == 0) {
      const float* hsrc = h0 + (size_t)dir * B_ * H_
                          + (size_t)(bg * 16 + sb) * H_;
#pragma unroll
      for (int p = 0; p < 4; ++p) {
        int u0 = (p * 32 + sk) * 4;
        unsigned lo = (unsigned)f2bf(hsrc[u0 + 0])
                    | ((unsigned)f2bf(hsrc[u0 + 1]) << 16);
        unsigned hi = (unsigned)f2bf(hsrc[u0 + 2])
                    | ((unsigned)f2bf(hsrc[u0 + 3]) << 16);
        hv[p] = (unsigned long long)lo | ((unsigned long long)hi << 32);
      }
    } else {
      hbq = (unsigned long long*)(hxc + (size_t)((s - 1) & 1) * 4096);
#pragma unroll
      for (int p = 0; p < 4; ++p)
        hv[p] = __hip_atomic_load(hbq + (p * 32 + sk), __ATOMIC_RELAXED,
                                  __HIP_MEMORY_SCOPE_AGENT);
    }
    __syncthreads();                             // Bs.x ready

    // x-part MFMAs (ktiles 0..11), two independent chains
    f32x4 aA = {0.f, 0.f, 0.f, 0.f}, aB = {0.f, 0.f, 0.f, 0.f};
#pragma unroll
    for (int kt = 0; kt < 12; kt += 2) {
      bf16x8 b0 = ((const bf16x8*)Bs)[kt * 64 + lane];
      bf16x8 b1 = ((const bf16x8*)Bs)[(kt + 1) * 64 + lane];
      aA = __builtin_amdgcn_mfma_f32_16x16x32_bf16(afrag[kt], b0, aA, 0, 0, 0);
      aB = __builtin_amdgcn_mfma_f32_16x16x32_bf16(afrag[kt + 1], b1, aB, 0, 0, 0);
    }

    // arrival check + retry; then re-poison exclusive replica
    if (s) {
      while (true) {
        bool ok = true;
#pragma unroll
        for (int p = 0; p < 4; ++p) {
          unsigned lo = (unsigned)hv[p], hi = (unsigned)(hv[p] >> 32);
          ok = ok && (lo != SENT_) && (hi != SENT_);
        }
        if (__all(ok)) break;
        __builtin_amdgcn_s_sleep(1);
#pragma unroll
        for (int p = 0; p < 4; ++p)
          hv[p] = __hip_atomic_load(hbq + (p * 32 + sk), __ATOMIC_RELAXED,
                                    __HIP_MEMORY_SCOPE_AGENT);
      }
#pragma unroll
      for (int p = 0; p < 4; ++p)
        __hip_atomic_store(hbq + (p * 32 + sk), 0xFFFFFFFFFFFFFFFFULL,
                           __ATOMIC_RELAXED, __HIP_MEMORY_SCOPE_AGENT);
    }

    // stage h part (ktiles 12..27): q = 96 + p*32 + sk
#pragma unroll
    for (int p = 0; p < 4; ++p) {
      int q = 96 + p * 32 + sk;
      Bs8[(q >> 3) * 128 + ((q >> 1) & 3) * 32 + sb * 2 + (q & 1)] = hv[p];
    }
    __syncthreads();                             // Bs.h ready

    // h-part MFMAs (ktiles 12..27)
#pragma unroll
    for (int kt = 12; kt < 28; kt += 2) {
      bf16x8 b0 = ((const bf16x8*)Bs)[kt * 64 + lane];
      bf16x8 b1 = ((const bf16x8*)Bs)[(kt + 1) * 64 + lane];
      aA = __builtin_amdgcn_mfma_f32_16x16x32_bf16(afrag[kt], b0, aA, 0, 0, 0);
      aB = __builtin_amdgcn_mfma_f32_16x16x32_bf16(afrag[kt + 1], b1, aB, 0, 0, 0);
    }

    float gi = aA[0] + aB[0] + bsv[0];
    float gf = aA[1] + aB[1] + bsv[1];
    float gg = aA[2] + aB[2] + bsv[2];
    float go = aA[3] + aB[3] + bsv[3];
    float si = 1.f / (1.f + __expf(-gi));
    float sf = 1.f / (1.f + __expf(-gf));
    float so = 1.f / (1.f + __expf(-go));
    c = sf * c + si * tanhf(gg);
    float h = so * tanhf(c);
    unsigned hb16 = f2bf(h);
    int partner = __shfl_xor((int)hb16, 16);

    if (s + 1 < T_) {
      // order re-poison (and all earlier stores) before publish
      asm volatile("s_waitcnt vmcnt(0)" ::: "memory");
      if (!(lane & 16)) {
        unsigned packed = hb16 | ((unsigned)partner << 16);
        unsigned* pb = hxp + (size_t)(s & 1) * 4096;
#pragma unroll
        for (int cg = 0; cg < 16; ++cg)
          __hip_atomic_store(pb + (size_t)cg * 8192, packed,
                             __ATOMIC_RELAXED, __HIP_MEMORY_SCOPE_AGENT);
      }
    }

    Hsc[(size_t)cur * B_ * 1024 + (size_t)bD * 1024 + dir * H_ + jD] =
        (unsigned short)hb16;

    if (s + 1 < T_) {
      // prefetch next x-slice (completion awaited at next Bs.x write)
      const int curn = dir ? (T_ - 2 - s) : (s + 1);
      const unsigned short* xsrc = x + (size_t)(curn * B_ + bg * 16 + sb) * EC_;
#pragma unroll
      for (int p = 0; p < 3; ++p)
        xv[p] = *(const unsigned long long*)(xsrc + (p * 32 + sk) * 4);
    }
  }
}

// ---------------- W_word bf16 MFMA fused tanh * w_proj -> logits -----------
__global__ __launch_bounds__(256) void k_wword(
    const unsigned short* __restrict__ Hsc, const unsigned short* __restrict__ wwT,
    const float* __restrict__ bw, const float* __restrict__ wp,
    float* __restrict__ logits) {
  const int lane = threadIdx.x & 63;
  const int wv   = threadIdx.x >> 6;             // 0..3
  const int db = blockIdx.x;                     // 0..7
  const int nb = blockIdx.y;                     // 0..511
  const int tokbase = nb * 64 + wv * 16;
  const int m = lane & 15, koct = lane >> 4;
  const unsigned short* aptr = Hsc + (size_t)(tokbase + m) * 1024 + koct * 8;
  const unsigned short* bptr = wwT + (size_t)(db * 128 + m) * 1024 + koct * 8;

  f32x4 acc[8];
#pragma unroll
  for (int dt = 0; dt < 8; ++dt) acc[dt] = (f32x4){0.f, 0.f, 0.f, 0.f};

  for (int k0 = 0; k0 < 1024; k0 += 32) {
    bf16x8 af = *(const bf16x8*)(aptr + k0);
#pragma unroll
    for (int dt = 0; dt < 8; ++dt) {
      bf16x8 bf = *(const bf16x8*)(bptr + (size_t)dt * 16 * 1024 + k0);
      acc[dt] = __builtin_amdgcn_mfma_f32_16x16x32_bf16(af, bf, acc[dt], 0, 0, 0);
    }
  }
  float rs[4] = {0.f, 0.f, 0.f, 0.f};
  const int d0 = db * 128 + (lane & 15);
#pragma unroll
  for (int dt = 0; dt < 8; ++dt) {
    float bwv = bw[d0 + dt * 16], wpv = wp[d0 + dt * 16];
#pragma unroll
    for (int q = 0; q < 4; ++q)
      rs[q] += tanhf(acc[dt][q] + bwv) * wpv;
  }
#pragma unroll
  for (int off = 1; off < 16; off <<= 1)
#pragma unroll
    for (int q = 0; q < 4; ++q) rs[q] += __shfl_xor(rs[q], off);
  if ((lane & 15) == 0) {
    const int tok = tokbase + (lane >> 4) * 4;
#pragma unroll
    for (int q = 0; q < 4; ++q) atomicAdd(&logits[tok + q], rs[q]);
  }
}

// ---------------- softmax over time (per batch column) ----------------
__global__ __launch_bounds__(256) void k_softmax(
    const float* __restrict__ logits, float* __restrict__ attn) {
  __shared__ float red[256];
  const int b = blockIdx.x, tid = threadIdx.x;
  float v0 = logits[(size_t)tid * B_ + b];
  float v1 = logits[(size_t)(tid + 256) * B_ + b];
  red[tid] = fmaxf(v0, v1);
  __syncthreads();
  for (int off = 128; off; off >>= 1) {
    if (tid < off) red[tid] = fmaxf(red[tid], red[tid + off]);
    __syncthreads();
  }
  float m = red[0];
  __syncthreads();
  float e0 = __expf(v0 - m), e1 = __expf(v1 - m);
  red[tid] = e0 + e1;
  __syncthreads();
  for (int off = 128; off; off >>= 1) {
    if (tid < off) red[tid] += red[tid + off];
    __syncthreads();
  }
  float inv = 1.f / red[0];
  attn[(size_t)tid * B_ + b] = e0 * inv;
  attn[(size_t)(tid + 256) * B_ + b] = e1 * inv;
}

// ---------------- ctx[b][d] = sum_t attn[t,b] * Hout[t,b,d] ----------------
__global__ __launch_bounds__(256) void k_ctx(
    const float* __restrict__ attn, const unsigned short* __restrict__ Hsc,
    float* __restrict__ ctx) {
  __shared__ float al[512];
  const int b = blockIdx.x, dc = blockIdx.y, tid = threadIdx.x;
  al[tid]       = attn[(size_t)tid * B_ + b];
  al[tid + 256] = attn[(size_t)(tid + 256) * B_ + b];
  __syncthreads();
  float acc = 0.f;
  const unsigned short* hp = Hsc + (size_t)b * 1024 + dc * 256 + tid;
#pragma unroll 8
  for (int t = 0; t < T_; ++t)
    acc = fmaf(al[t], bf2f(hp[(size_t)t * B_ * 1024]), acc);
  ctx[b * 1024 + dc * 256 + tid] = acc;
}

// ---------------- final linear: out[b][c] ----------------
__global__ __launch_bounds__(64) void k_out(
    const float* __restrict__ ctx, const float* __restrict__ linW,
    const float* __restrict__ linb, float* __restrict__ out) {
  const int b = blockIdx.x, lane = threadIdx.x;
#pragma unroll
  for (int cc = 0; cc < NCLS; ++cc) {
    float p = 0.f;
    for (int d = lane; d < 1024; d += 64)
      p = fmaf(ctx[b * 1024 + d], linW[cc * 1024 + d], p);
    for (int off = 32; off; off >>= 1) p += __shfl_down(p, off);
    if (lane == 0) out[b * NCLS + cc] = p + linb[cc];
  }
}

// ---------------------------------------------------------------------------
extern "C" void kernel_launch(void* const* d_in, const int* in_sizes, int n_in,
                              void* d_out, int out_size, void* d_ws, size_t ws_size,
                              hipStream_t stream) {
  float* out = (float*)d_out;
  if (ws_size < WS_REQ) {
    k_sentinel<<<(out_size + 63) / 64, 64, 0, stream>>>(
        out, out_size, (float)(ws_size >> 20));
    return;
  }
  const int*   embed   = (const int*)d_in[0];
  const float* c_embed = (const float*)d_in[1];
  const float* h0      = (const float*)d_in[2];
  const float* c0      = (const float*)d_in[3];
  const float* etab    = (const float*)d_in[4];
  const float* w_ih_f  = (const float*)d_in[5];
  const float* w_hh_f  = (const float*)d_in[6];
  const float* b_f     = (const float*)d_in[7];
  const float* w_ih_b  = (const float*)d_in[8];
  const float* w_hh_b  = (const float*)d_in[9];
  const float* b_b     = (const float*)d_in[10];
  const float* W_word  = (const float*)d_in[11];
  const float* b_word  = (const float*)d_in[12];
  const float* w_proj  = (const float*)d_in[13];
  const float* lin_W   = (const float*)d_in[14];
  const float* lin_b   = (const float*)d_in[15];

  char* W = (char*)d_ws;
  unsigned short* x    = (unsigned short*)(W + OFF_X);
  unsigned short* Hsc  = (unsigned short*)(W + OFF_HSC);
  float*          logits = (float*)(W + OFF_LOG);
  float*          attn   = (float*)(W + OFF_ATTN);
  float*          ctx    = (float*)(W + OFF_CTX);
  unsigned short* wwT    = (unsigned short*)(W + OFF_WWT);
  unsigned*       hx     = (unsigned*)(W + OFF_HX);

  // zero logits (atomic target); sentinel-fill hx (graph-replay-safe)
  hipMemsetAsync(logits, 0, NTOK * sizeof(float), stream);
  hipMemsetAsync(hx, 0xFF, 16777216, stream);

  k_gather <<<6144, 256, 0, stream>>>(embed, c_embed, etab, x);
  k_cvtw   <<<256, 256, 0, stream>>>(W_word, wwT);
  k_scan   <<<128, 512, 0, stream>>>(x, w_ih_f, w_hh_f, w_ih_b, w_hh_b,
                                     b_f, b_b, h0, c0, Hsc, hx);
  k_wword  <<<dim3(8, 512), 256, 0, stream>>>(Hsc, wwT, b_word, w_proj, logits);
  k_softmax<<<64, 256, 0, stream>>>(logits, attn);
  k_ctx    <<<dim3(64, 4), 256, 0, stream>>>(attn, Hsc, ctx);
  k_out    <<<64, 64, 0, stream>>>(ctx, lin_W, lin_b, out);
}

// Round 11
// 1871.004 us; speedup vs baseline: 4.1018x; 4.1018x over previous
//
#include <hip/hip_runtime.h>
#include <cstdint>
#include <cstddef>

// ---------------------------------------------------------------------------
// AttentionWordRNN on MI355X — ROUND 8: generation-tagged h exchange.
// Round-7 post-mortem: 16x replication + re-poison + 1KB-strided publishes =
// 5.3GB write traffic at ~950GB/s = the whole kernel. Fix: NO replication, NO
// re-poison, NO flags. 2 parity buffers; each published dword carries a 1-bit
// generation tag g=(s>>1)&1 in the LSB of the even-j bf16. Stale vs fresh is
// decided by tag; overwrite safety follows from consume-before-publish
// causality (all wgs consumed t-2 before anyone publishes t). Publishes are
// line-coalesced ([ug][jl][b] layout); hx shrinks 16MB -> 256KB (IF$-hot).
// ---------------------------------------------------------------------------

#define T_    512
#define B_    64
#define E_    256
#define CD_   128
#define EC_   384      // E + CDIM
#define H_    512
#define NCLS  5
#define NTOK  32768    // T*B

// byte offsets into d_ws
#define OFF_X      0UL
#define OFF_HSC    25165824UL
#define OFF_LOG    92274688UL
#define OFF_ATTN   92405760UL
#define OFF_CTX    92536832UL
#define OFF_WWT    92798976UL
#define OFF_HX     94896128UL
#define WS_REQ     95158272UL

typedef __attribute__((ext_vector_type(8))) short bf16x8;
typedef __attribute__((ext_vector_type(4))) float f32x4;

__device__ __forceinline__ unsigned short f2bf(float f) {
  union { float f; unsigned u; } v; v.f = f;
  unsigned r = v.u + 0x7FFFu + ((v.u >> 16) & 1u);   // RNE
  return (unsigned short)(r >> 16);
}
__device__ __forceinline__ float bf2f(unsigned short h) {
  union { unsigned u; float f; } v; v.u = ((unsigned)h) << 16;
  return v.f;
}

// ---------------- ws-too-small sentinel ----------------
__global__ void k_sentinel(float* __restrict__ out, int n, float val) {
  int i = blockIdx.x * 64 + threadIdx.x;
  if (i < n) out[i] = val;
}

// ---------------- gather + concat -> x bf16 [NTOK][384] ----------------
__global__ __launch_bounds__(256) void k_gather(
    const int* __restrict__ embed, const float* __restrict__ c_embed,
    const float* __restrict__ etab, unsigned short* __restrict__ x) {
  int idx = blockIdx.x * 256 + threadIdx.x;     // NTOK*48 exact
  int n = idx / 48;
  int q8 = idx - n * 48;
  float f[8];
  if (q8 < 32) {
    int tok = embed[n];
    const float* src = etab + (size_t)tok * E_ + q8 * 8;
#pragma unroll
    for (int j = 0; j < 8; ++j) f[j] = src[j];
  } else {
    const float* src = c_embed + (size_t)n * CD_ + (q8 - 32) * 8;
#pragma unroll
    for (int j = 0; j < 8; ++j) f[j] = src[j];
  }
  union { uint4 v; unsigned short s[8]; } u;
#pragma unroll
  for (int j = 0; j < 8; ++j) u.s[j] = f2bf(f[j]);
  *(uint4*)(x + (size_t)n * EC_ + q8 * 8) = u.v;
}

// ---------------- W_word fp32 [k][d] -> bf16 transposed wwT [d][k] ---------
__global__ __launch_bounds__(256) void k_cvtw(
    const float* __restrict__ Ww, unsigned short* __restrict__ wwT) {
  __shared__ float t[64][65];
  const int kb = blockIdx.x >> 4, db = blockIdx.x & 15;
  const int r = threadIdx.x >> 4, c4 = (threadIdx.x & 15) * 4;
#pragma unroll
  for (int p = 0; p < 4; ++p) {
    float4 v = *(const float4*)(Ww + (size_t)(kb * 64 + p * 16 + r) * 1024
                                + db * 64 + c4);
    t[p * 16 + r][c4 + 0] = v.x; t[p * 16 + r][c4 + 1] = v.y;
    t[p * 16 + r][c4 + 2] = v.z; t[p * 16 + r][c4 + 3] = v.w;
  }
  __syncthreads();
#pragma unroll
  for (int p = 0; p < 4; ++p) {
    union { ushort4 v; unsigned short s[4]; } o;
#pragma unroll
    for (int j = 0; j < 4; ++j) o.s[j] = f2bf(t[c4 + j][p * 16 + r]);
    *(ushort4*)(wwT + (size_t)(db * 64 + p * 16 + r) * 1024 + kb * 64 + c4) = o.v;
  }
}

// ---------------- fused biLSTM scan: x_proj + recurrence, MFMA ----------------
// 128 wgs of 512 thr = dir(2) x bg(4) x ug(16, 32 units); grp = gid&7.
// hx layout: [par(2)][grp(8)][ug(16)][jl(16)][b(16)] dwords, 256 KB total.
// Publish: tagged dword (LSB of even-j bf16 = (s>>1)&1), line-coalesced.
// Consume: poll own 8 dwords for tag match; no flags/fences/re-poison.
__global__ __launch_bounds__(512) void k_scan(
    const unsigned short* __restrict__ x,
    const float* __restrict__ wih_f, const float* __restrict__ whh_f,
    const float* __restrict__ wih_b, const float* __restrict__ whh_b,
    const float* __restrict__ bias_f, const float* __restrict__ bias_b,
    const float* __restrict__ h0, const float* __restrict__ c0,
    unsigned short* __restrict__ Hsc,            // [T][B][1024] bf16
    unsigned* __restrict__ hx) {
  __shared__ uint4 Bs[1792];                     // 28 ktiles x 64 lanes x 16B
  unsigned long long* const Bs8 = (unsigned long long*)Bs;
  const int tid  = threadIdx.x;
  const int lane = tid & 63;
  const int w    = tid >> 6;                     // wave 0..7
  const int gid  = blockIdx.x;
  const int grp  = gid & 7;                      // dir*4+bg
  const int ug   = gid >> 3;                     // 0..15
  const int dir  = grp >> 2;
  const int bg   = grp & 3;

  const float* wih  = dir ? wih_b  : wih_f;      // [2048][384]
  const float* whh  = dir ? whh_b  : whh_f;      // [2048][512]
  const float* bias = dir ? bias_b : bias_f;     // [2048]

  // ---- preload A fragments (bf16) into registers ----
  bf16x8 afrag[28];
  {
    const int m = lane & 15, koct = lane >> 4;   // A-role: row, k-octet
    const int grow = (m & 3) * H_ + ug * 32 + w * 4 + (m >> 2);
#pragma unroll
    for (int kt = 0; kt < 12; ++kt) {
      const float* src = wih + (size_t)grow * EC_ + kt * 32 + koct * 8;
      union { bf16x8 v; unsigned short s[8]; } u;
#pragma unroll
      for (int j = 0; j < 8; ++j) u.s[j] = f2bf(src[j]);
      afrag[kt] = u.v;
    }
#pragma unroll
    for (int kt = 0; kt < 16; ++kt) {
      const float* src = whh + (size_t)grow * H_ + kt * 32 + koct * 8;
      union { bf16x8 v; unsigned short s[8]; } u;
#pragma unroll
      for (int j = 0; j < 8; ++j) u.s[j] = f2bf(src[j]);
      afrag[12 + kt] = u.v;
    }
  }

  // ---- D-role lane identity: (unit, batch); c-state in register ----
  const int bD = bg * 16 + (lane & 15);
  const int jD = ug * 32 + w * 4 + (lane >> 4);
  float bsv[4];
#pragma unroll
  for (int q = 0; q < 4; ++q) bsv[q] = bias[q * H_ + jD];
  float c = c0[(size_t)dir * B_ * H_ + (size_t)bD * H_ + jD];

  const int sb = tid & 15;                       // staging: batch row
  const int sk = tid >> 4;                       // staging: 0..31

  // producer slot (lanes bit4==0): [ug][jl = w*2 + (lane>>5)][b = lane&15]
  unsigned* const hxp = hx + (size_t)grp * 4096
                        + ug * 256 + (w * 2 + (lane >> 5)) * 16 + (lane & 15);
  // consumer offsets: 2 dwords per p at [ug'][jl'][sb], jl' even
  const unsigned* const hxc = hx + (size_t)grp * 4096;
  const int coff0 = (sk >> 3) * 256 + (sk & 7) * 32 + sb;  // + p*1024, +16

  // prefetch x-slice for step 0
  unsigned long long xv[3];
  {
    const int cur0 = dir ? (T_ - 1) : 0;
    const unsigned short* xsrc = x + (size_t)(cur0 * B_ + bg * 16 + sb) * EC_;
#pragma unroll
    for (int p = 0; p < 3; ++p)
      xv[p] = *(const unsigned long long*)(xsrc + (p * 32 + sk) * 4);
  }

  for (int s = 0; s < T_; ++s) {
    const int cur = dir ? (T_ - 1 - s) : s;
    const unsigned gpub = (unsigned)((s >> 1) & 1);
    const unsigned gexp = (unsigned)(((s - 1) >> 1) & 1);
    __syncthreads();                             // all waves done with prev Bs
    // stage x part (ktiles 0..11): q = p*32+sk
#pragma unroll
    for (int p = 0; p < 3; ++p) {
      int q = p * 32 + sk;
      Bs8[(q >> 3) * 128 + ((q >> 1) & 3) * 32 + sb * 2 + (q & 1)] = xv[p];
    }

    // issue h reads optimistically (tag-checked after x-MFMAs)
    unsigned lo[4], hi[4];
    const unsigned* hbq = nullptr;
    if (s == 0) {
      const float* hsrc = h0 + (size_t)dir * B_ * H_
                          + (size_t)(bg * 16 + sb) * H_;
#pragma unroll
      for (int p = 0; p < 4; ++p) {
        int u0 = (p * 32 + sk) * 4;
        lo[p] = (unsigned)f2bf(hsrc[u0 + 0])
              | ((unsigned)f2bf(hsrc[u0 + 1]) << 16);
        hi[p] = (unsigned)f2bf(hsrc[u0 + 2])
              | ((unsigned)f2bf(hsrc[u0 + 3]) << 16);
      }
    } else {
      hbq = hxc + (size_t)((s - 1) & 1) * 32768;
#pragma unroll
      for (int p = 0; p < 4; ++p) {
        lo[p] = __hip_atomic_load(hbq + coff0 + p * 1024, __ATOMIC_RELAXED,
                                  __HIP_MEMORY_SCOPE_AGENT);
        hi[p] = __hip_atomic_load(hbq + coff0 + p * 1024 + 16, __ATOMIC_RELAXED,
                                  __HIP_MEMORY_SCOPE_AGENT);
      }
    }
    __syncthreads();                             // Bs.x ready

    // x-part MFMAs (ktiles 0..11), two independent chains
    f32x4 aA = {0.f, 0.f, 0.f, 0.f}, aB = {0.f, 0.f, 0.f, 0.f};
#pragma unroll
    for (int kt = 0; kt < 12; kt += 2) {
      bf16x8 b0 = ((const bf16x8*)Bs)[kt * 64 + lane];
      bf16x8 b1 = ((const bf16x8*)Bs)[(kt + 1) * 64 + lane];
      aA = __builtin_amdgcn_mfma_f32_16x16x32_bf16(afrag[kt], b0, aA, 0, 0, 0);
      aB = __builtin_amdgcn_mfma_f32_16x16x32_bf16(afrag[kt + 1], b1, aB, 0, 0, 0);
    }

    // tag check + retry (arrival == generation match on every dword)
    if (s) {
      while (true) {
        bool ok = true;
#pragma unroll
        for (int p = 0; p < 4; ++p)
          ok = ok && ((lo[p] & 1u) == gexp) && ((hi[p] & 1u) == gexp);
        if (__all(ok)) break;
        __builtin_amdgcn_s_sleep(1);
#pragma unroll
        for (int p = 0; p < 4; ++p) {
          lo[p] = __hip_atomic_load(hbq + coff0 + p * 1024, __ATOMIC_RELAXED,
                                    __HIP_MEMORY_SCOPE_AGENT);
          hi[p] = __hip_atomic_load(hbq + coff0 + p * 1024 + 16, __ATOMIC_RELAXED,
                                    __HIP_MEMORY_SCOPE_AGENT);
        }
      }
    }

    // stage h part (ktiles 12..27): q = 96 + p*32 + sk
#pragma unroll
    for (int p = 0; p < 4; ++p) {
      int q = 96 + p * 32 + sk;
      Bs8[(q >> 3) * 128 + ((q >> 1) & 3) * 32 + sb * 2 + (q & 1)] =
          (unsigned long long)lo[p] | ((unsigned long long)hi[p] << 32);
    }
    __syncthreads();                             // Bs.h ready

    // h-part MFMAs (ktiles 12..27)
#pragma unroll
    for (int kt = 12; kt < 28; kt += 2) {
      bf16x8 b0 = ((const bf16x8*)Bs)[kt * 64 + lane];
      bf16x8 b1 = ((const bf16x8*)Bs)[(kt + 1) * 64 + lane];
      aA = __builtin_amdgcn_mfma_f32_16x16x32_bf16(afrag[kt], b0, aA, 0, 0, 0);
      aB = __builtin_amdgcn_mfma_f32_16x16x32_bf16(afrag[kt + 1], b1, aB, 0, 0, 0);
    }

    float gi = aA[0] + aB[0] + bsv[0];
    float gf = aA[1] + aB[1] + bsv[1];
    float gg = aA[2] + aB[2] + bsv[2];
    float go = aA[3] + aB[3] + bsv[3];
    float si = 1.f / (1.f + __expf(-gi));
    float sf = 1.f / (1.f + __expf(-gf));
    float so = 1.f / (1.f + __expf(-go));
    c = sf * c + si * tanhf(gg);
    float h = so * tanhf(c);
    unsigned hb16 = f2bf(h);
    int partner = __shfl_xor((int)hb16, 16);

    // publish tagged h pair (even-j LSB = gpub); data-dependency orders it
    if (s + 1 < T_ && !(lane & 16)) {
      unsigned packed = ((hb16 & ~1u) | gpub) | ((unsigned)partner << 16);
      __hip_atomic_store(hxp + (size_t)(s & 1) * 32768, packed,
                         __ATOMIC_RELAXED, __HIP_MEMORY_SCOPE_AGENT);
    }

    Hsc[(size_t)cur * B_ * 1024 + (size_t)bD * 1024 + dir * H_ + jD] =
        (unsigned short)hb16;

    if (s + 1 < T_) {
      // prefetch next x-slice (completion awaited at next Bs.x write)
      const int curn = dir ? (T_ - 2 - s) : (s + 1);
      const unsigned short* xsrc = x + (size_t)(curn * B_ + bg * 16 + sb) * EC_;
#pragma unroll
      for (int p = 0; p < 3; ++p)
        xv[p] = *(const unsigned long long*)(xsrc + (p * 32 + sk) * 4);
    }
  }
}

// ---------------- W_word bf16 MFMA fused tanh * w_proj -> logits -----------
__global__ __launch_bounds__(256) void k_wword(
    const unsigned short* __restrict__ Hsc, const unsigned short* __restrict__ wwT,
    const float* __restrict__ bw, const float* __restrict__ wp,
    float* __restrict__ logits) {
  const int lane = threadIdx.x & 63;
  const int wv   = threadIdx.x >> 6;             // 0..3
  const int db = blockIdx.x;                     // 0..7
  const int nb = blockIdx.y;                     // 0..511
  const int tokbase = nb * 64 + wv * 16;
  const int m = lane & 15, koct = lane >> 4;
  const unsigned short* aptr = Hsc + (size_t)(tokbase + m) * 1024 + koct * 8;
  const unsigned short* bptr = wwT + (size_t)(db * 128 + m) * 1024 + koct * 8;

  f32x4 acc[8];
#pragma unroll
  for (int dt = 0; dt < 8; ++dt) acc[dt] = (f32x4){0.f, 0.f, 0.f, 0.f};

  for (int k0 = 0; k0 < 1024; k0 += 32) {
    bf16x8 af = *(const bf16x8*)(aptr + k0);
#pragma unroll
    for (int dt = 0; dt < 8; ++dt) {
      bf16x8 bf = *(const bf16x8*)(bptr + (size_t)dt * 16 * 1024 + k0);
      acc[dt] = __builtin_amdgcn_mfma_f32_16x16x32_bf16(af, bf, acc[dt], 0, 0, 0);
    }
  }
  float rs[4] = {0.f, 0.f, 0.f, 0.f};
  const int d0 = db * 128 + (lane & 15);
#pragma unroll
  for (int dt = 0; dt < 8; ++dt) {
    float bwv = bw[d0 + dt * 16], wpv = wp[d0 + dt * 16];
#pragma unroll
    for (int q = 0; q < 4; ++q)
      rs[q] += tanhf(acc[dt][q] + bwv) * wpv;
  }
#pragma unroll
  for (int off = 1; off < 16; off <<= 1)
#pragma unroll
    for (int q = 0; q < 4; ++q) rs[q] += __shfl_xor(rs[q], off);
  if ((lane & 15) == 0) {
    const int tok = tokbase + (lane >> 4) * 4;
#pragma unroll
    for (int q = 0; q < 4; ++q) atomicAdd(&logits[tok + q], rs[q]);
  }
}

// ---------------- softmax over time (per batch column) ----------------
__global__ __launch_bounds__(256) void k_softmax(
    const float* __restrict__ logits, float* __restrict__ attn) {
  __shared__ float red[256];
  const int b = blockIdx.x, tid = threadIdx.x;
  float v0 = logits[(size_t)tid * B_ + b];
  float v1 = logits[(size_t)(tid + 256) * B_ + b];
  red[tid] = fmaxf(v0, v1);
  __syncthreads();
  for (int off = 128; off; off >>= 1) {
    if (tid < off) red[tid] = fmaxf(red[tid], red[tid + off]);
    __syncthreads();
  }
  float m = red[0];
  __syncthreads();
  float e0 = __expf(v0 - m), e1 = __expf(v1 - m);
  red[tid] = e0 + e1;
  __syncthreads();
  for (int off = 128; off; off >>= 1) {
    if (tid < off) red[tid] += red[tid + off];
    __syncthreads();
  }
  float inv = 1.f / red[0];
  attn[(size_t)tid * B_ + b] = e0 * inv;
  attn[(size_t)(tid + 256) * B_ + b] = e1 * inv;
}

// ---------------- ctx[b][d] = sum_t attn[t,b] * Hout[t,b,d] ----------------
__global__ __launch_bounds__(256) void k_ctx(
    const float* __restrict__ attn, const unsigned short* __restrict__ Hsc,
    float* __restrict__ ctx) {
  __shared__ float al[512];
  const int b = blockIdx.x, dc = blockIdx.y, tid = threadIdx.x;
  al[tid]       = attn[(size_t)tid * B_ + b];
  al[tid + 256] = attn[(size_t)(tid + 256) * B_ + b];
  __syncthreads();
  float acc = 0.f;
  const unsigned short* hp = Hsc + (size_t)b * 1024 + dc * 256 + tid;
#pragma unroll 8
  for (int t = 0; t < T_; ++t)
    acc = fmaf(al[t], bf2f(hp[(size_t)t * B_ * 1024]), acc);
  ctx[b * 1024 + dc * 256 + tid] = acc;
}

// ---------------- final linear: out[b][c] ----------------
__global__ __launch_bounds__(64) void k_out(
    const float* __restrict__ ctx, const float* __restrict__ linW,
    const float* __restrict__ linb, float* __restrict__ out) {
  const int b = blockIdx.x, lane = threadIdx.x;
#pragma unroll
  for (int cc = 0; cc < NCLS; ++cc) {
    float p = 0.f;
    for (int d = lane; d < 1024; d += 64)
      p = fmaf(ctx[b * 1024 + d], linW[cc * 1024 + d], p);
    for (int off = 32; off; off >>= 1) p += __shfl_down(p, off);
    if (lane == 0) out[b * NCLS + cc] = p + linb[cc];
  }
}

// ---------------------------------------------------------------------------
extern "C" void kernel_launch(void* const* d_in, const int* in_sizes, int n_in,
                              void* d_out, int out_size, void* d_ws, size_t ws_size,
                              hipStream_t stream) {
  float* out = (float*)d_out;
  if (ws_size < WS_REQ) {
    k_sentinel<<<(out_size + 63) / 64, 64, 0, stream>>>(
        out, out_size, (float)(ws_size >> 20));
    return;
  }
  const int*   embed   = (const int*)d_in[0];
  const float* c_embed = (const float*)d_in[1];
  const float* h0      = (const float*)d_in[2];
  const float* c0      = (const float*)d_in[3];
  const float* etab    = (const float*)d_in[4];
  const float* w_ih_f  = (const float*)d_in[5];
  const float* w_hh_f  = (const float*)d_in[6];
  const float* b_f     = (const float*)d_in[7];
  const float* w_ih_b  = (const float*)d_in[8];
  const float* w_hh_b  = (const float*)d_in[9];
  const float* b_b     = (const float*)d_in[10];
  const float* W_word  = (const float*)d_in[11];
  const float* b_word  = (const float*)d_in[12];
  const float* w_proj  = (const float*)d_in[13];
  const float* lin_W   = (const float*)d_in[14];
  const float* lin_b   = (const float*)d_in[15];

  char* W = (char*)d_ws;
  unsigned short* x    = (unsigned short*)(W + OFF_X);
  unsigned short* Hsc  = (unsigned short*)(W + OFF_HSC);
  float*          logits = (float*)(W + OFF_LOG);
  float*          attn   = (float*)(W + OFF_ATTN);
  float*          ctx    = (float*)(W + OFF_CTX);
  unsigned short* wwT    = (unsigned short*)(W + OFF_WWT);
  unsigned*       hx     = (unsigned*)(W + OFF_HX);

  // zero logits (atomic target); tag-1-fill hx (graph-replay-safe:
  // g(0)=g(1)=0, so 0xFF lines can never satisfy the first polls)
  hipMemsetAsync(logits, 0, NTOK * sizeof(float), stream);
  hipMemsetAsync(hx, 0xFF, 262144, stream);

  k_gather <<<6144, 256, 0, stream>>>(embed, c_embed, etab, x);
  k_cvtw   <<<256, 256, 0, stream>>>(W_word, wwT);
  k_scan   <<<128, 512, 0, stream>>>(x, w_ih_f, w_hh_f, w_ih_b, w_hh_b,
                                     b_f, b_b, h0, c0, Hsc, hx);
  k_wword  <<<dim3(8, 512), 256, 0, stream>>>(Hsc, wwT, b_word, w_proj, logits);
  k_softmax<<<64, 256, 0, stream>>>(logits, attn);
  k_ctx    <<<dim3(64, 4), 256, 0, stream>>>(attn, Hsc, ctx);
  k_out    <<<64, 64, 0, stream>>>(ctx, lin_W, lin_b, out);
}